// Round 1
// baseline (204.249 us; speedup 1.0000x reference)
//
#include <hip/hip_runtime.h>

// Dual-quaternion skinning, one thread per point. N=500000, K=8.
// Memory-bound: 532B read + 48B write per point => ~290MB/launch, roofline ~46us.

__device__ __forceinline__ void quat2mat(float qw, float qx, float qy, float qz, float R[9]) {
    // Scale-invariant form of quaternion_to_matrix(normalize(q)): two_s = 2/|q|^2
    float s  = qw*qw + qx*qx + qy*qy + qz*qz;
    float ts = 2.0f / s;
    R[0] = 1.0f - ts*(qy*qy + qz*qz);
    R[1] = ts*(qx*qy - qz*qw);
    R[2] = ts*(qx*qz + qy*qw);
    R[3] = ts*(qx*qy + qz*qw);
    R[4] = 1.0f - ts*(qx*qx + qz*qz);
    R[5] = ts*(qy*qz - qx*qw);
    R[6] = ts*(qx*qz - qy*qw);
    R[7] = ts*(qy*qz + qx*qw);
    R[8] = 1.0f - ts*(qx*qx + qy*qy);
}

__global__ void __launch_bounds__(256) dqskin_kernel(
    const float* __restrict__ sk_w,     // [N,8]
    const float* __restrict__ src_xyz,  // [N,3]
    const float* __restrict__ s_xyz,    // [N,8,3]
    const float* __restrict__ s_quat,   // [N,8,4] (w,x,y,z)
    const float* __restrict__ d_xyz,    // [N,8,3]
    const float* __restrict__ d_quat,   // [N,8,4]
    const float* __restrict__ dyn_o,    // [N]
    const float* __restrict__ src_R,    // [N,3,3]
    float* __restrict__ out,            // mu [N,3] then fr [N,3,3]
    int N)
{
    int n = blockIdx.x * blockDim.x + threadIdx.x;
    if (n >= N) return;

    const float4* qs4 = reinterpret_cast<const float4*>(s_quat) + (size_t)n * 8;
    const float4* qd4 = reinterpret_cast<const float4*>(d_quat) + (size_t)n * 8;
    const float4* w4  = reinterpret_cast<const float4*>(sk_w)  + (size_t)n * 2;

    float4 wa = w4[0], wb = w4[1];
    float wk[8] = {wa.x, wa.y, wa.z, wa.w, wb.x, wb.y, wb.z, wb.w};

    const float* sx = s_xyz + (size_t)n * 24;
    const float* dx = d_xyz + (size_t)n * 24;

    float acc[8] = {0.f,0.f,0.f,0.f,0.f,0.f,0.f,0.f};

    #pragma unroll
    for (int k = 0; k < 8; ++k) {
        float4 qi = qs4[k];   // (w,x,y,z)
        float4 qj = qd4[k];
        float Ri[9], Rj[9];
        quat2mat(qi.x, qi.y, qi.z, qi.w, Ri);
        quat2mat(qj.x, qj.y, qj.z, qj.w, Rj);

        // R_ji = R_wj * R_wi^T   (einsum nsij,nskj->nsik)
        float R[9];
        #pragma unroll
        for (int i = 0; i < 3; ++i) {
            #pragma unroll
            for (int c = 0; c < 3; ++c) {
                R[i*3+c] = Rj[i*3+0]*Ri[c*3+0] + Rj[i*3+1]*Ri[c*3+1] + Rj[i*3+2]*Ri[c*3+2];
            }
        }

        float px = sx[k*3+0], py = sx[k*3+1], pz = sx[k*3+2];
        float t0 = dx[k*3+0] - (R[0]*px + R[1]*py + R[2]*pz);
        float t1 = dx[k*3+1] - (R[3]*px + R[4]*py + R[5]*pz);
        float t2 = dx[k*3+2] - (R[6]*px + R[7]*py + R[8]*pz);

        // matrix_to_quaternion(R)
        float a0 = sqrtf(fmaxf(1.0f + R[0] + R[4] + R[8], 0.0f));
        float a1 = sqrtf(fmaxf(1.0f + R[0] - R[4] - R[8], 0.0f));
        float a2 = sqrtf(fmaxf(1.0f - R[0] + R[4] - R[8], 0.0f));
        float a3 = sqrtf(fmaxf(1.0f - R[0] - R[4] + R[8], 0.0f));
        int idx = 0; float best = a0;                  // first-max tie-break == jnp.argmax
        if (a1 > best) { best = a1; idx = 1; }
        if (a2 > best) { best = a2; idx = 2; }
        if (a3 > best) { best = a3; idx = 3; }

        float m01 = R[1], m02 = R[2], m10 = R[3], m12 = R[5], m20 = R[6], m21 = R[7];
        // candidate rows (selected component-wise, branchless)
        float cw = idx==0 ? a0*a0   : idx==1 ? m21-m12 : idx==2 ? m02-m20 : m10-m01;
        float cx = idx==0 ? m21-m12 : idx==1 ? a1*a1   : idx==2 ? m10+m01 : m20+m02;
        float cy = idx==0 ? m02-m20 : idx==1 ? m10+m01 : idx==2 ? a2*a2   : m21+m12;
        float cz = idx==0 ? m10-m01 : idx==1 ? m02+m20 : idx==2 ? m12+m21 : a3*a3;
        float inv = 1.0f / fmaxf(2.0f * best, 0.1f);
        float qrw = cw*inv, qrx = cx*inv, qry = cy*inv, qrz = cz*inv;

        // qd = 0.5 * qmul([0,t], qr)
        float qdw = 0.5f * (-t0*qrx - t1*qry - t2*qrz);
        float qdx = 0.5f * ( t0*qrw + t1*qrz - t2*qry);
        float qdy = 0.5f * (-t0*qrz + t1*qrw + t2*qrx);
        float qdz = 0.5f * ( t0*qry - t1*qrx + t2*qrw);

        float w_ = wk[k];
        acc[0] += w_*qrw; acc[1] += w_*qrx; acc[2] += w_*qry; acc[3] += w_*qrz;
        acc[4] += w_*qdw; acc[5] += w_*qdx; acc[6] += w_*qdy; acc[7] += w_*qdz;
    }

    // blend with identity dq by dyn_o
    float o = dyn_o[n];
    #pragma unroll
    for (int i = 0; i < 8; ++i) acc[i] *= o;
    acc[0] += 1.0f - o;

    // dq2unitdq
    float nr = sqrtf(acc[0]*acc[0] + acc[1]*acc[1] + acc[2]*acc[2] + acc[3]*acc[3]);
    nr = fmaxf(nr, 1e-4f);   // DQ_EPS
    float inr = 1.0f / nr;
    float qrw = acc[0]*inr, qrx = acc[1]*inr, qry = acc[2]*inr, qrz = acc[3]*inr;
    float qdw = acc[4]*inr, qdx = acc[5]*inr, qdy = acc[6]*inr, qdz = acc[7]*inr;
    float dp = qrw*qdw + qrx*qdx + qry*qdy + qrz*qdz;
    qdw -= dp*qrw; qdx -= dp*qrx; qdy -= dp*qry; qdz -= dp*qrz;

    // dq2Rt
    float Rt[9];
    quat2mat(qrw, qrx, qry, qrz, Rt);
    float tx = 2.0f * (-qdw*qrx + qdx*qrw - qdy*qrz + qdz*qry);
    float ty = 2.0f * (-qdw*qry + qdx*qrz + qdy*qrw - qdz*qrx);
    float tz = 2.0f * (-qdw*qrz - qdx*qry + qdy*qrx + qdz*qrw);

    // mu_dst = Rt @ src_xyz + t
    float px = src_xyz[(size_t)n*3+0];
    float py = src_xyz[(size_t)n*3+1];
    float pz = src_xyz[(size_t)n*3+2];
    out[(size_t)n*3+0] = Rt[0]*px + Rt[1]*py + Rt[2]*pz + tx;
    out[(size_t)n*3+1] = Rt[3]*px + Rt[4]*py + Rt[5]*pz + ty;
    out[(size_t)n*3+2] = Rt[6]*px + Rt[7]*py + Rt[8]*pz + tz;

    // fr_dst = Rt @ src_R
    const float* M = src_R + (size_t)n * 9;
    float m0=M[0],m1=M[1],m2=M[2],m3=M[3],m4=M[4],m5=M[5],m6=M[6],m7=M[7],m8=M[8];
    float* fo = out + (size_t)N * 3 + (size_t)n * 9;
    fo[0] = Rt[0]*m0 + Rt[1]*m3 + Rt[2]*m6;
    fo[1] = Rt[0]*m1 + Rt[1]*m4 + Rt[2]*m7;
    fo[2] = Rt[0]*m2 + Rt[1]*m5 + Rt[2]*m8;
    fo[3] = Rt[3]*m0 + Rt[4]*m3 + Rt[5]*m6;
    fo[4] = Rt[3]*m1 + Rt[4]*m4 + Rt[5]*m7;
    fo[5] = Rt[3]*m2 + Rt[4]*m5 + Rt[5]*m8;
    fo[6] = Rt[6]*m0 + Rt[7]*m3 + Rt[8]*m6;
    fo[7] = Rt[6]*m1 + Rt[7]*m4 + Rt[8]*m7;
    fo[8] = Rt[6]*m2 + Rt[7]*m5 + Rt[8]*m8;
}

extern "C" void kernel_launch(void* const* d_in, const int* in_sizes, int n_in,
                              void* d_out, int out_size, void* d_ws, size_t ws_size,
                              hipStream_t stream) {
    const float* sk_w    = (const float*)d_in[0];
    const float* src_xyz = (const float*)d_in[1];
    const float* s_xyz   = (const float*)d_in[2];
    const float* s_quat  = (const float*)d_in[3];
    const float* d_xyz   = (const float*)d_in[4];
    const float* d_quat  = (const float*)d_in[5];
    const float* dyn_o   = (const float*)d_in[6];
    const float* src_R   = (const float*)d_in[7];
    int N = in_sizes[6];   // dyn_o is [N]
    float* out = (float*)d_out;

    int blocks = (N + 255) / 256;
    hipLaunchKernelGGL(dqskin_kernel, dim3(blocks), dim3(256), 0, stream,
                       sk_w, src_xyz, s_xyz, s_quat, d_xyz, d_quat, dyn_o, src_R, out, N);
}

// Round 2
// 64.892 us; speedup vs baseline: 3.1475x; 3.1475x over previous
//
#include <hip/hip_runtime.h>

// Dual-quaternion skinning, one thread per point. N=500000, K=8.
// Round 2: quats staged to LDS via global_load_lds (exactly-once fetch),
// XOR-swizzled source / XOR-swizzled read (bank-conflict-free), xyz as
// float4 register bursts. Memory roofline ~46us at 6.3 TB/s.

typedef const __attribute__((address_space(1))) void* gas1_t;
typedef __attribute__((address_space(3))) void* las3_t;

__device__ __forceinline__ void quat2mat(float qw, float qx, float qy, float qz, float R[9]) {
    // Scale-invariant form of quaternion_to_matrix(normalize(q)): two_s = 2/|q|^2
    float s  = qw*qw + qx*qx + qy*qy + qz*qz;
    float ts = 2.0f / s;
    R[0] = 1.0f - ts*(qy*qy + qz*qz);
    R[1] = ts*(qx*qy - qz*qw);
    R[2] = ts*(qx*qz + qy*qw);
    R[3] = ts*(qx*qy + qz*qw);
    R[4] = 1.0f - ts*(qx*qx + qz*qz);
    R[5] = ts*(qy*qz - qx*qw);
    R[6] = ts*(qx*qz - qy*qw);
    R[7] = ts*(qy*qz + qx*qw);
    R[8] = 1.0f - ts*(qx*qx + qy*qy);
}

// Stage one 128 B/point array chunk for this block into LDS.
// LDS dest is LINEAR (global_load_lds requirement); the global source chunk
// index is XOR-permuted (involution within 64-chunk/1KB groups) so that the
// swizzled READ (slot = t*8 + (k ^ (t&7))) returns global chunk t*8+k.
__device__ __forceinline__ void stage_quat_swz(const float* __restrict__ g,
                                               float* lds, long long n0,
                                               long long Ntot, int tid) {
    const char* gbase = (const char*)g;
    long long maxaddr = Ntot * 128 - 16;   // clamp for tail block (no OOB)
    int wave = tid >> 6;
    #pragma unroll
    for (int it = 0; it < 8; ++it) {
        int s   = it * 256 + tid;              // linear LDS chunk slot
        int gch = s ^ ((s >> 3) & 7);          // pre-swizzled global chunk
        long long addr = n0 * 128 + (long long)gch * 16;
        addr = addr > maxaddr ? maxaddr : addr;
        char* ldst = (char*)lds + (size_t)(it * 256 + wave * 64) * 16; // wave-uniform
        __builtin_amdgcn_global_load_lds((gas1_t)(gbase + addr), (las3_t)ldst, 16, 0, 0);
    }
}

__global__ void __launch_bounds__(256, 2) dqskin_kernel(
    const float* __restrict__ sk_w,     // [N,8]
    const float* __restrict__ src_xyz,  // [N,3]
    const float* __restrict__ s_xyz,    // [N,8,3]
    const float* __restrict__ s_quat,   // [N,8,4] (w,x,y,z)
    const float* __restrict__ d_xyz,    // [N,8,3]
    const float* __restrict__ d_quat,   // [N,8,4]
    const float* __restrict__ dyn_o,    // [N]
    const float* __restrict__ src_R,    // [N,3,3]
    float* __restrict__ out,            // mu [N,3] then fr [N,3,3]
    int N)
{
    __shared__ float lds_sq[8192];   // 32 KB
    __shared__ float lds_dq[8192];   // 32 KB  (total 64 KB -> 2 blocks/CU)

    int tid = threadIdx.x;
    long long n0 = (long long)blockIdx.x * 256;
    long long n  = n0 + tid;
    bool valid = n < N;
    long long nc = valid ? n : (N - 1);   // clamped index for loads

    // ---- issue direct-to-LDS staging of both quat arrays (exactly-once fetch)
    stage_quat_swz(s_quat, lds_sq, n0, N, tid);
    stage_quat_swz(d_quat, lds_dq, n0, N, tid);

    // ---- per-thread register loads (tight float4 bursts)
    const float4* sx4 = reinterpret_cast<const float4*>(s_xyz + nc * 24);
    const float4* dx4 = reinterpret_cast<const float4*>(d_xyz + nc * 24);
    float4 sxv[6], dxv[6];
    #pragma unroll
    for (int i = 0; i < 6; ++i) { sxv[i] = sx4[i]; dxv[i] = dx4[i]; }
    const float* sxf = reinterpret_cast<const float*>(sxv);
    const float* dxf = reinterpret_cast<const float*>(dxv);

    const float4* w4 = reinterpret_cast<const float4*>(sk_w) + nc * 2;
    float4 wa = w4[0], wb = w4[1];
    const float w8[8] = {wa.x, wa.y, wa.z, wa.w, wb.x, wb.y, wb.z, wb.w};

    asm volatile("s_waitcnt vmcnt(0)");
    __syncthreads();

    const float4* sq4 = reinterpret_cast<const float4*>(lds_sq);
    const float4* dq4 = reinterpret_cast<const float4*>(lds_dq);
    int t7 = tid & 7;

    float acc[8] = {0.f,0.f,0.f,0.f,0.f,0.f,0.f,0.f};

    #pragma unroll
    for (int k = 0; k < 8; ++k) {
        float4 qi = sq4[tid * 8 + (k ^ t7)];   // swizzled read -> global chunk tid*8+k
        float4 qj = dq4[tid * 8 + (k ^ t7)];
        float Ri[9], Rj[9];
        quat2mat(qi.x, qi.y, qi.z, qi.w, Ri);
        quat2mat(qj.x, qj.y, qj.z, qj.w, Rj);

        // R_ji = R_wj * R_wi^T   (einsum nsij,nskj->nsik)
        float R[9];
        #pragma unroll
        for (int i = 0; i < 3; ++i)
            #pragma unroll
            for (int c = 0; c < 3; ++c)
                R[i*3+c] = Rj[i*3+0]*Ri[c*3+0] + Rj[i*3+1]*Ri[c*3+1] + Rj[i*3+2]*Ri[c*3+2];

        float px = sxf[k*3+0], py = sxf[k*3+1], pz = sxf[k*3+2];
        float t0 = dxf[k*3+0] - (R[0]*px + R[1]*py + R[2]*pz);
        float t1 = dxf[k*3+1] - (R[3]*px + R[4]*py + R[5]*pz);
        float t2 = dxf[k*3+2] - (R[6]*px + R[7]*py + R[8]*pz);

        // matrix_to_quaternion(R)
        float a0 = sqrtf(fmaxf(1.0f + R[0] + R[4] + R[8], 0.0f));
        float a1 = sqrtf(fmaxf(1.0f + R[0] - R[4] - R[8], 0.0f));
        float a2 = sqrtf(fmaxf(1.0f - R[0] + R[4] - R[8], 0.0f));
        float a3 = sqrtf(fmaxf(1.0f - R[0] - R[4] + R[8], 0.0f));
        int idx = 0; float best = a0;                  // first-max tie-break == jnp.argmax
        if (a1 > best) { best = a1; idx = 1; }
        if (a2 > best) { best = a2; idx = 2; }
        if (a3 > best) { best = a3; idx = 3; }

        float m01 = R[1], m02 = R[2], m10 = R[3], m12 = R[5], m20 = R[6], m21 = R[7];
        float cw = idx==0 ? a0*a0   : idx==1 ? m21-m12 : idx==2 ? m02-m20 : m10-m01;
        float cx = idx==0 ? m21-m12 : idx==1 ? a1*a1   : idx==2 ? m10+m01 : m20+m02;
        float cy = idx==0 ? m02-m20 : idx==1 ? m10+m01 : idx==2 ? a2*a2   : m21+m12;
        float cz = idx==0 ? m10-m01 : idx==1 ? m02+m20 : idx==2 ? m12+m21 : a3*a3;
        float inv = 1.0f / fmaxf(2.0f * best, 0.1f);
        float qrw = cw*inv, qrx = cx*inv, qry = cy*inv, qrz = cz*inv;

        // qd = 0.5 * qmul([0,t], qr)
        float qdw = 0.5f * (-t0*qrx - t1*qry - t2*qrz);
        float qdx = 0.5f * ( t0*qrw + t1*qrz - t2*qry);
        float qdy = 0.5f * (-t0*qrz + t1*qrw + t2*qrx);
        float qdz = 0.5f * ( t0*qry - t1*qrx + t2*qrw);

        float w_ = w8[k];
        acc[0] += w_*qrw; acc[1] += w_*qrx; acc[2] += w_*qry; acc[3] += w_*qrz;
        acc[4] += w_*qdw; acc[5] += w_*qdx; acc[6] += w_*qdy; acc[7] += w_*qdz;
    }

    // blend with identity dq by dyn_o
    float o = dyn_o[nc];
    #pragma unroll
    for (int i = 0; i < 8; ++i) acc[i] *= o;
    acc[0] += 1.0f - o;

    // dq2unitdq
    float nr = sqrtf(acc[0]*acc[0] + acc[1]*acc[1] + acc[2]*acc[2] + acc[3]*acc[3]);
    nr = fmaxf(nr, 1e-4f);   // DQ_EPS
    float inr = 1.0f / nr;
    float qrw = acc[0]*inr, qrx = acc[1]*inr, qry = acc[2]*inr, qrz = acc[3]*inr;
    float qdw = acc[4]*inr, qdx = acc[5]*inr, qdy = acc[6]*inr, qdz = acc[7]*inr;
    float dp = qrw*qdw + qrx*qdx + qry*qdy + qrz*qdz;
    qdw -= dp*qrw; qdx -= dp*qrx; qdy -= dp*qry; qdz -= dp*qrz;

    // dq2Rt
    float Rt[9];
    quat2mat(qrw, qrx, qry, qrz, Rt);
    float tx = 2.0f * (-qdw*qrx + qdx*qrw - qdy*qrz + qdz*qry);
    float ty = 2.0f * (-qdw*qry + qdx*qrz + qdy*qrw - qdz*qrx);
    float tz = 2.0f * (-qdw*qrz - qdx*qry + qdy*qrx + qdz*qrw);

    // mu_dst = Rt @ src_xyz + t
    float px = src_xyz[nc*3+0];
    float py = src_xyz[nc*3+1];
    float pz = src_xyz[nc*3+2];
    float mu0 = Rt[0]*px + Rt[1]*py + Rt[2]*pz + tx;
    float mu1 = Rt[3]*px + Rt[4]*py + Rt[5]*pz + ty;
    float mu2 = Rt[6]*px + Rt[7]*py + Rt[8]*pz + tz;

    // fr_dst = Rt @ src_R
    const float* M = src_R + nc * 9;
    float m0=M[0],m1=M[1],m2=M[2],m3=M[3],m4=M[4],m5=M[5],m6=M[6],m7=M[7],m8=M[8];

    if (valid) {
        out[n*3+0] = mu0; out[n*3+1] = mu1; out[n*3+2] = mu2;
        float* fo = out + (size_t)N * 3 + n * 9;
        fo[0] = Rt[0]*m0 + Rt[1]*m3 + Rt[2]*m6;
        fo[1] = Rt[0]*m1 + Rt[1]*m4 + Rt[2]*m7;
        fo[2] = Rt[0]*m2 + Rt[1]*m5 + Rt[2]*m8;
        fo[3] = Rt[3]*m0 + Rt[4]*m3 + Rt[5]*m6;
        fo[4] = Rt[3]*m1 + Rt[4]*m4 + Rt[5]*m7;
        fo[5] = Rt[3]*m2 + Rt[4]*m5 + Rt[5]*m8;
        fo[6] = Rt[6]*m0 + Rt[7]*m3 + Rt[8]*m6;
        fo[7] = Rt[6]*m1 + Rt[7]*m4 + Rt[8]*m7;
        fo[8] = Rt[6]*m2 + Rt[7]*m5 + Rt[8]*m8;
    }
}

extern "C" void kernel_launch(void* const* d_in, const int* in_sizes, int n_in,
                              void* d_out, int out_size, void* d_ws, size_t ws_size,
                              hipStream_t stream) {
    const float* sk_w    = (const float*)d_in[0];
    const float* src_xyz = (const float*)d_in[1];
    const float* s_xyz   = (const float*)d_in[2];
    const float* s_quat  = (const float*)d_in[3];
    const float* d_xyz   = (const float*)d_in[4];
    const float* d_quat  = (const float*)d_in[5];
    const float* dyn_o   = (const float*)d_in[6];
    const float* src_R   = (const float*)d_in[7];
    int N = in_sizes[6];   // dyn_o is [N]
    float* out = (float*)d_out;

    int blocks = (N + 255) / 256;
    hipLaunchKernelGGL(dqskin_kernel, dim3(blocks), dim3(256), 0, stream,
                       sk_w, src_xyz, s_xyz, s_quat, d_xyz, d_quat, dyn_o, src_R, out, N);
}